// Round 18
// baseline (126.126 us; speedup 1.0000x reference)
//
#include <hip/hip_runtime.h>
#include <math.h>

#define NTHR 512
#define NB 4              // batches per WG (kernel1)
#define NROWSR (NB * 20)  // 80 rows = 5 exact M-tiles

typedef _Float16 h8v __attribute__((ext_vector_type(8)));
typedef _Float16 h2v __attribute__((ext_vector_type(2)));
using f4 = __attribute__((ext_vector_type(4))) float;

__device__ __forceinline__ h2v cvt_pk_h2(float a, float b) {
  return __builtin_bit_cast(h2v, __builtin_amdgcn_cvt_pkrtz(a, b));
}

// kernel1 LDS pool (bytes). Single-plane f16: [rows][PK], 2B/elem.
#define H1_OFF 0
#define H1_PK 168        // 80*168*2 = 26880
#define H2_OFF 26880
#define H2_PK 136        // 80*136*2 = 21760 -> end 48640
#define FEAT_OFF 0       // aliases H1 (dead after L2)
#define FEAT_PK 136
#define S1_OFF 26880     // aliases H2 (dead after L3); [112,128) zeros inherited
#define S1_PK 136
#define XS_OFF 26880     // aliases H2 region during P0/P1 only
#define XS_PK 40         // 80*40*2 = 6400
#define GS_OFF S1_OFF    // GS16: 4 rows x PK136 f16, alive P4->P5 only
#define POOL1 48640

// ws fragment bases (1KB blocks; each (kb,nt) = 2 blocks hi+lo)
#define L1B 0
#define L2B 20
#define L3B 90
#define A1B 146
#define A2B 202
#define M1B 258
#define M2B 338
#define M3B 408
#define A1GB 464          // a1 rows 100..199 (gpart MFMA): 4kb x 7nt x 2
#define BIAS_BYTE 532480  // 520KB: packed f16 biases, 8 regions x 160 ushorts
#define JOINT_BYTE 536576 // f16 joint[16384][106]

// bias region offsets (ushorts)
#define BO_B1 0
#define BO_B2 160
#define BO_B3 320
#define BO_AB1 480
#define BO_MB1 800
#define BO_MB2 960
#define BO_MB3 1120

// kernel2 (f16 single-plane)
#define K2ROWS 64
#define K2THR 256
#define K2_JT_OFF 0      // 64*136*2 = 17408
#define K2_V1_OFF 17408  // 64*168*2 = 21504 -> end 38912
#define K2_POOL 38912

__device__ __forceinline__ float relu_f(float v) { return fmaxf(v, 0.f); }
__device__ __forceinline__ float h2f(ushort u) {
  return (float)__builtin_bit_cast(_Float16, u);
}
__device__ __forceinline__ ushort f2h(float v) {
  return __builtin_bit_cast(ushort, (_Float16)v);
}
__device__ __forceinline__ uint pk2h(float a, float b) {
  return (uint)f2h(a) | ((uint)f2h(b) << 16);
}

// guarded float4 (zeros beyond C)
__device__ __forceinline__ float4 load4_guard(const float* __restrict__ a, int of4, int C) {
  float4 v;
  if (of4 + 3 < C) v = *(const float4*)(a + of4);
  else {
    v.x = (of4 + 0 < C) ? a[of4 + 0] : 0.f;
    v.y = (of4 + 1 < C) ? a[of4 + 1] : 0.f;
    v.z = (of4 + 2 < C) ? a[of4 + 2] : 0.f;
    v.w = (of4 + 3 < C) ? a[of4 + 3] : 0.f;
  }
  return v;
}

// ---------------- prep: pack hi/lo f16 weight fragments + f16 biases ---------
__global__ __launch_bounds__(64) void prep_kernel(
    const float* __restrict__ w1, const float* __restrict__ w2,
    const float* __restrict__ w3, const float* __restrict__ a1,
    const float* __restrict__ a2, const float* __restrict__ m1,
    const float* __restrict__ m2, const float* __restrict__ m3,
    const float* __restrict__ b1, const float* __restrict__ b2,
    const float* __restrict__ b3, const float* __restrict__ ab1,
    const float* __restrict__ mb1, const float* __restrict__ mb2,
    const float* __restrict__ mb3,
    uint4* __restrict__ ws) {
  const int job = blockIdx.x;
  const int lane = threadIdx.x;
  if (job == 260) {  // pack biases -> f16 (zero-padded to 160 each)
    ushort* bh = (ushort*)((char*)ws + BIAS_BYTE);
    for (int idx = lane; idx < 1280; idx += 64) {
      const int reg = idx / 160, off = idx - reg * 160;
      const float* src = nullptr; int C = 0;
      switch (reg) {
        case 0: src = b1;  C = 150; break;
        case 1: src = b2;  C = 100; break;
        case 2: src = b3;  C = 100; break;
        case 3: src = ab1; C = 100; break;
        case 4: src = nullptr; C = 0; break;   // (spare)
        case 5: src = mb1; C = 150; break;
        case 6: src = mb2; C = 100; break;
        default: src = mb3; C = 100; break;
      }
      bh[idx] = (off < C) ? f2h(src[off]) : (ushort)0;
    }
    return;
  }
  const float* W;
  int K, C, NT, base, kb, nt, i;
  if (job < 10)       { W = w1; K = 13;  C = 150; NT = 10; base = L1B; kb = 0; nt = job; }
  else if (job < 45)  { W = w2; K = 150; C = 100; NT = 7;  base = L2B; i = job - 10;  kb = i / 7;  nt = i % 7; }
  else if (job < 73)  { W = w3; K = 100; C = 100; NT = 7;  base = L3B; i = job - 45;  kb = i / 7;  nt = i % 7; }
  else if (job < 101) { W = a1; K = 100; C = 100; NT = 7;  base = A1B; i = job - 73;  kb = i / 7;  nt = i % 7; }
  else if (job < 129) { W = a2; K = 100; C = 100; NT = 7;  base = A2B; i = job - 101; kb = i / 7;  nt = i % 7; }
  else if (job < 169) { W = m1; K = 106; C = 150; NT = 10; base = M1B; i = job - 129; kb = i / 10; nt = i % 10; }
  else if (job < 204) { W = m2; K = 150; C = 100; NT = 7;  base = M2B; i = job - 169; kb = i / 7;  nt = i % 7; }
  else if (job < 232) { W = m3; K = 100; C = 100; NT = 7;  base = M3B; i = job - 204; kb = i / 7;  nt = i % 7; }
  else                { W = a1 + 10000; K = 100; C = 100; NT = 7; base = A1GB; i = job - 232; kb = i / 7; nt = i % 7; }
  const int r = lane & 15, g = lane >> 4;
  const int j = nt * 16 + r;
  uint hi[8], lo[8];
  for (int e = 0; e < 8; ++e) {
    int k = kb * 32 + g * 8 + e;
    float v = (k < K && j < C) ? W[k * C + j] : 0.f;
    _Float16 hh = (_Float16)v;
    float hf = (float)hh;
    _Float16 ll = (_Float16)(v - hf);
    hi[e] = (uint)__builtin_bit_cast(ushort, hh);
    lo[e] = (uint)__builtin_bit_cast(ushort, ll);
  }
  uint4 vh = { hi[0] | (hi[1] << 16), hi[2] | (hi[3] << 16),
               hi[4] | (hi[5] << 16), hi[6] | (hi[7] << 16) };
  uint4 vl = { lo[0] | (lo[1] << 16), lo[2] | (lo[3] << 16),
               lo[4] | (lo[5] << 16), lo[6] | (lo[7] << 16) };
  ws[(size_t)(base + (kb * NT + nt) * 2 + 0) * 64 + lane] = vh;
  ws[(size_t)(base + (kb * NT + nt) * 2 + 1) * 64 + lane] = vl;
}

// ---------------- f16 MFMA dense layer, swapped operands ----------------
// D = W^T x act^T: lane holds 4 consecutive out-features (of..of+3) of ONE
// act row. Packed-f16 epilogue; pad cols compute to exact 0.
// PAIR=true (kernel1): wave owns an nt-PAIR; act fragment read once per mt
// feeds both nt (halves ds_read + addressing). Fits VGPR cap only at TERMS=1.
// TERMS: 1 = single f16 weight term, 2 = hi/lo compensated.
// MODE: 0 relu->f16, 1 linear->f16, 2 relu+gpart->f16,
//       3 relu + a3-dot fold -> sceL atomics (f32 path, biasF)
template <int KB, int NT, int C, int MODE, int ROWS, bool W8, int TERMS, bool PAIR>
__device__ __forceinline__ void mfma_layer(
    char* pool, int inOff, int PKin, int outOff, int PKout,
    const h8v* __restrict__ wsB, const ushort* __restrict__ biasH,
    const float* __restrict__ biasF, const ushort* gpartH, float* sceL,
    const float* __restrict__ a3, int lane, int wid) {
  constexpr int MTL = ROWS / 16;
  const int r = lane & 15, g = lane >> 4;
  const char* Ain = pool + inOff;
  int wlo, mtb, mte;
  if constexpr (W8) {
    wlo = wid & 3;
    const int whi = wid >> 2;
    mtb = whi ? 3 : 0; mte = whi ? MTL : 3;
  } else { wlo = wid; mtb = 0; mte = MTL; }

  if constexpr (PAIR) {
    constexpr int NP2 = (NT + 1) / 2;
    for (int p = wlo; p < NP2; p += 4) {
      const int nt0 = 2 * p;
      const bool two = (nt0 + 1 < NT);
      h8v w0[KB], w1[KB];
#pragma unroll
      for (int kb = 0; kb < KB; ++kb) {
        w0[kb] = wsB[((kb * NT + nt0) * 2 + 0) * 64 + lane];
        if (two) w1[kb] = wsB[((kb * NT + nt0 + 1) * 2 + 0) * 64 + lane];
      }
      const int of0 = nt0 * 16 + g * 4, of1 = of0 + 16;
      uint2 bp0, bp1;
      float4 b40, b41, a340, a341;
      if constexpr (MODE == 3) {
        b40 = load4_guard(biasF, of0, C); a340 = load4_guard(a3, of0, C);
        b41 = load4_guard(biasF, of1, C); a341 = load4_guard(a3, of1, C);
      } else {
        bp0 = *(const uint2*)(biasH + of0);
        bp1 = *(const uint2*)(biasH + of1);   // biasH zero-padded to 160
      }
      for (int mt = mtb; mt < mte; ++mt) {
        const int ar = mt * 16 + r;
        f4 acc0 = {0.f, 0.f, 0.f, 0.f}, acc1 = {0.f, 0.f, 0.f, 0.f};
        const char* aP = Ain + ar * (PKin * 2) + g * 16;
#pragma unroll
        for (int kb = 0; kb < KB; ++kb) {
          h8v a = *(const h8v*)(aP + kb * 64);
          acc0 = __builtin_amdgcn_mfma_f32_16x16x32_f16(w0[kb], a, acc0, 0, 0, 0);
          if (two) acc1 = __builtin_amdgcn_mfma_f32_16x16x32_f16(w1[kb], a, acc1, 0, 0, 0);
        }
        if constexpr (MODE == 3) {
          float v0 = fmaxf(acc0[0] + b40.x, 0.f), v1 = fmaxf(acc0[1] + b40.y, 0.f);
          float v2 = fmaxf(acc0[2] + b40.z, 0.f), v3 = fmaxf(acc0[3] + b40.w, 0.f);
          float val = v0 * a340.x + v1 * a340.y + v2 * a340.z + v3 * a340.w;
          if (two) {
            float u0 = fmaxf(acc1[0] + b41.x, 0.f), u1 = fmaxf(acc1[1] + b41.y, 0.f);
            float u2 = fmaxf(acc1[2] + b41.z, 0.f), u3 = fmaxf(acc1[3] + b41.w, 0.f);
            val += u0 * a341.x + u1 * a341.y + u2 * a341.z + u3 * a341.w;
          }
          val += __shfl_xor(val, 16);
          val += __shfl_xor(val, 32);
          if (lane < 16) atomicAdd(&sceL[ar], val);
        } else {
          h2v lo = cvt_pk_h2(acc0[0], acc0[1]);
          h2v hi = cvt_pk_h2(acc0[2], acc0[3]);
          lo += __builtin_bit_cast(h2v, bp0.x);
          hi += __builtin_bit_cast(h2v, bp0.y);
          if constexpr (MODE == 2) {
            uint2 gp = *(const uint2*)(gpartH + (ar / 20) * 112 + of0);
            lo += __builtin_bit_cast(h2v, gp.x);
            hi += __builtin_bit_cast(h2v, gp.y);
          }
          if constexpr (MODE != 1) {
            h2v z = {(_Float16)0.f, (_Float16)0.f};
            lo = __builtin_elementwise_max(lo, z);
            hi = __builtin_elementwise_max(hi, z);
          }
          *(uint2*)((ushort*)(pool + outOff) + ar * PKout + of0) =
              uint2{__builtin_bit_cast(uint, lo), __builtin_bit_cast(uint, hi)};
          if (two) {
            h2v lo1 = cvt_pk_h2(acc1[0], acc1[1]);
            h2v hi1 = cvt_pk_h2(acc1[2], acc1[3]);
            lo1 += __builtin_bit_cast(h2v, bp1.x);
            hi1 += __builtin_bit_cast(h2v, bp1.y);
            if constexpr (MODE == 2) {
              uint2 gp1 = *(const uint2*)(gpartH + (ar / 20) * 112 + of1);
              lo1 += __builtin_bit_cast(h2v, gp1.x);
              hi1 += __builtin_bit_cast(h2v, gp1.y);
            }
            if constexpr (MODE != 1) {
              h2v z = {(_Float16)0.f, (_Float16)0.f};
              lo1 = __builtin_elementwise_max(lo1, z);
              hi1 = __builtin_elementwise_max(hi1, z);
            }
            *(uint2*)((ushort*)(pool + outOff) + ar * PKout + of1) =
                uint2{__builtin_bit_cast(uint, lo1), __builtin_bit_cast(uint, hi1)};
          }
        }
      }
    }
  } else {
    for (int nt = wlo; nt < NT; nt += 4) {
      h8v wh[KB], wl[KB];
#pragma unroll
      for (int kb = 0; kb < KB; ++kb) {
        wh[kb] = wsB[((kb * NT + nt) * 2 + 0) * 64 + lane];
        if constexpr (TERMS == 2)
          wl[kb] = wsB[((kb * NT + nt) * 2 + 1) * 64 + lane];
      }
      const int of = nt * 16 + g * 4;
      uint2 bp;
      float4 b4, a34;
      if constexpr (MODE == 3) {
        b4 = load4_guard(biasF, of, C);
        a34 = load4_guard(a3, of, C);
      } else {
        bp = *(const uint2*)(biasH + of);
      }
      for (int mt = mtb; mt < mte; ++mt) {
        const int ar = mt * 16 + r;
        f4 acc = {0.f, 0.f, 0.f, 0.f};
        const char* aP = Ain + ar * (PKin * 2) + g * 16;
#pragma unroll
        for (int kb = 0; kb < KB; ++kb) {
          h8v a = *(const h8v*)(aP + kb * 64);
          acc = __builtin_amdgcn_mfma_f32_16x16x32_f16(wh[kb], a, acc, 0, 0, 0);
          if constexpr (TERMS == 2)
            acc = __builtin_amdgcn_mfma_f32_16x16x32_f16(wl[kb], a, acc, 0, 0, 0);
        }
        if constexpr (MODE == 3) {
          float v0 = fmaxf(acc[0] + b4.x, 0.f), v1 = fmaxf(acc[1] + b4.y, 0.f);
          float v2 = fmaxf(acc[2] + b4.z, 0.f), v3 = fmaxf(acc[3] + b4.w, 0.f);
          float val = v0 * a34.x + v1 * a34.y + v2 * a34.z + v3 * a34.w;
          val += __shfl_xor(val, 16);
          val += __shfl_xor(val, 32);
          if (lane < 16) atomicAdd(&sceL[ar], val);
        } else {
          h2v lo = cvt_pk_h2(acc[0], acc[1]);
          h2v hi = cvt_pk_h2(acc[2], acc[3]);
          lo += __builtin_bit_cast(h2v, bp.x);
          hi += __builtin_bit_cast(h2v, bp.y);
          if constexpr (MODE == 2) {
            uint2 gp = *(const uint2*)(gpartH + (ar / 20) * 112 + of);
            lo += __builtin_bit_cast(h2v, gp.x);
            hi += __builtin_bit_cast(h2v, gp.y);
          }
          if constexpr (MODE != 1) {
            h2v z = {(_Float16)0.f, (_Float16)0.f};
            lo = __builtin_elementwise_max(lo, z);
            hi = __builtin_elementwise_max(hi, z);
          }
          *(uint2*)((ushort*)(pool + outOff) + ar * PKout + of) =
              uint2{__builtin_bit_cast(uint, lo), __builtin_bit_cast(uint, hi)};
        }
      }
    }
  }
}

// zero cols [112,128) of an f16 [ROWSZ][PK] buffer
template <int ROWSZ, int PK>
__device__ __forceinline__ void zero_tail(char* pool, int off, int tid) {
  if (tid < ROWSZ) {
    uint4* z = (uint4*)((ushort*)(pool + off) + (size_t)tid * PK + 112);
    z[0] = uint4{0, 0, 0, 0};
    z[1] = uint4{0, 0, 0, 0};
  }
}

// ---------------- kernel1: 4 batches per 512-thr WG ----------------
__global__ __launch_bounds__(NTHR, 6) void value_net_kernel(
    const float* __restrict__ state,
    const float* __restrict__ ab2,
    const float* __restrict__ a3, const float* __restrict__ ab3,
    const uint4* __restrict__ ws, ushort* __restrict__ jointgH) {
  __shared__ char pool[POOL1];
  __shared__ ushort gpartH[NB * 112];
  __shared__ float sceL[NROWSR];

  const int tid = threadIdx.x;
  const int lane = tid & 63, wid = tid >> 6;
  const int b0 = blockIdx.x * NB;
  const h8v* wsb = (const h8v*)ws;
  const ushort* biasH = (const ushort*)((const char*)ws + BIAS_BYTE);

  // P0: stage state -> XS f16 (80 x PK40, cols 13..39 zero); zero sceL
  for (int i = tid; i < NROWSR * XS_PK; i += NTHR) {
    int row = i / XS_PK, k = i - row * XS_PK;
    float v = (k < 13) ? state[((size_t)b0 * 20 + row) * 13 + k] : 0.f;
    ((ushort*)(pool + XS_OFF))[row * XS_PK + k] = f2h(v);
  }
  if (tid < NROWSR) sceL[tid] = 0.f;
  __syncthreads();

  // P1: L1 13->150 relu  XS -> H1
  mfma_layer<1, 10, 150, 0, NROWSR, true, 1, true>(
      pool, XS_OFF, XS_PK, H1_OFF, H1_PK, wsb + L1B * 64, biasH + BO_B1,
      nullptr, nullptr, nullptr, nullptr, lane, wid);
  __syncthreads();

  // P2: zero H2 tail; L2 150->100 relu  H1 -> H2
  zero_tail<NROWSR, H2_PK>(pool, H2_OFF, tid);
  mfma_layer<5, 7, 100, 0, NROWSR, true, 1, true>(
      pool, H1_OFF, H1_PK, H2_OFF, H2_PK, wsb + L2B * 64, biasH + BO_B2,
      nullptr, nullptr, nullptr, nullptr, lane, wid);
  __syncthreads();

  // P3: zero FEAT tail; L3 100->100 linear  H2 -> FEAT
  zero_tail<NROWSR, FEAT_PK>(pool, FEAT_OFF, tid);
  mfma_layer<4, 7, 100, 1, NROWSR, true, 1, true>(
      pool, H2_OFF, H2_PK, FEAT_OFF, FEAT_PK, wsb + L3B * 64, biasH + BO_B3,
      nullptr, nullptr, nullptr, nullptr, lane, wid);
  __syncthreads();

  // P4: gs = mean over n (x0.05) -> GS16 f16 tile (cols [100,128) zero)
  if (tid < NB * 100) {
    const int b = tid / 100, d = tid - b * 100;
    const ushort* f = (const ushort*)(pool + FEAT_OFF);
    float s = 0.f;
    for (int n = 0; n < 20; ++n) s += h2f(f[(b * 20 + n) * FEAT_PK + d]);
    ((ushort*)(pool + GS_OFF))[b * 136 + d] = f2h(s * 0.05f);
  } else if (tid < NB * 100 + NB * 28) {
    const int idx = tid - NB * 100;
    ((ushort*)(pool + GS_OFF))[(idx / 28) * 136 + 100 + (idx % 28)] = 0;
  }
  __syncthreads();

  // P5: gpart = gs @ a1[100:200] via MFMA -> gpartH f16 (stride 112, pad 0)
  if (wid < 7) {
    const int r = lane & 15, g = lane >> 4;
    const int nt = wid;
    const h8v* wsg = wsb + A1GB * 64;
    h8v wh[4];
#pragma unroll
    for (int kb = 0; kb < 4; ++kb)
      wh[kb] = wsg[((kb * 7 + nt) * 2 + 0) * 64 + lane];
    const char* aP = pool + GS_OFF + (r & 3) * (136 * 2) + g * 16;
    f4 acc = {0.f, 0.f, 0.f, 0.f};
#pragma unroll
    for (int kb = 0; kb < 4; ++kb) {
      h8v a = *(const h8v*)(aP + kb * 64);
      acc = __builtin_amdgcn_mfma_f32_16x16x32_f16(wh[kb], a, acc, 0, 0, 0);
    }
    const int of = nt * 16 + g * 4;
    if (r < 4) {
      uint2 pk = { pk2h(acc[0], acc[1]), pk2h(acc[2], acc[3]) };
      *(uint2*)(gpartH + r * 112 + of) = pk;
    }
  }
  __syncthreads();

  // P6: A1 (feat half) + gpart, relu  FEAT -> S1
  mfma_layer<4, 7, 100, 2, NROWSR, true, 1, true>(
      pool, FEAT_OFF, FEAT_PK, S1_OFF, S1_PK, wsb + A1B * 64, biasH + BO_AB1,
      nullptr, gpartH, nullptr, nullptr, lane, wid);
  __syncthreads();

  // P7: A2 relu + A3-dot fold -> sceL atomics (f32 path)
  mfma_layer<4, 7, 100, 3, NROWSR, true, 1, true>(
      pool, S1_OFF, S1_PK, 0, 0, wsb + A2B * 64, nullptr,
      ab2, nullptr, sceL, a3, lane, wid);
  __syncthreads();

  // P8+P9 merged: one wave per batch; softmax via 64-lane butterflies,
  // sw passed to wf loop via __shfl (register-only, no barrier needed).
  if (wid < NB) {
    const int b = wid;
    const float ab3v = ab3[0];
    float s = (lane < 20) ? relu_f(sceL[b * 20 + lane] + ab3v) : -1e30f;
    float m = s;
#pragma unroll
    for (int d = 1; d < 64; d <<= 1) m = fmaxf(m, __shfl_xor(m, d));
    float e = (lane < 20) ? __expf(s - m) : 0.f;
    float sum = e;
#pragma unroll
    for (int d = 1; d < 64; d <<= 1) sum += __shfl_xor(sum, d);
    const float rinv = 1.f / sum;
    const ushort* f = (const ushort*)(pool + FEAT_OFF);
    const int d0 = lane, d1 = lane + 64;
    float acc0 = 0.f, acc1 = 0.f;
    for (int n = 0; n < 20; ++n) {
      const float swn = __shfl(e, n) * rinv;
      const ushort* frow = f + (b * 20 + n) * FEAT_PK;
      acc0 += swn * h2f(frow[d0]);
      if (d1 < 100) acc1 += swn * h2f(frow[d1]);
    }
    ushort* jb = jointgH + (size_t)(b0 + b) * 106;
    if (d0 < 100) jb[6 + d0] = f2h(acc0);
    if (d1 < 100) jb[6 + d1] = f2h(acc1);
    if (lane < 6) jb[lane] = f2h(state[((size_t)(b0 + b)) * 260 + lane]);
  }
}

// ---------------- kernel2: M-MLP GEMM over 16384 rows (f16, 2-term) ----------
__global__ __launch_bounds__(K2THR) void mlp2_kernel(
    const ushort* __restrict__ jointgH,
    const float* __restrict__ m4, const float* __restrict__ mb4,
    const uint4* __restrict__ ws, float* __restrict__ out) {
  __shared__ char pool[K2_POOL];
  __shared__ float m4L[100];
  const int tid = threadIdx.x, lane = tid & 63, wid = tid >> 6;
  const size_t r0 = (size_t)blockIdx.x * K2ROWS;
  const h8v* wsb = (const h8v*)ws;
  const ushort* biasH = (const ushort*)((const char*)ws + BIAS_BYTE);

  // stage joint f16 -> LDS (PK=136, cols 106..135 zero); m4 -> LDS
  for (int i = tid; i < K2ROWS * 136; i += K2THR) {
    int row = i / 136, k = i - row * 136;
    ((ushort*)(pool + K2_JT_OFF))[row * 136 + k] =
        (k < 106) ? jointgH[(r0 + row) * 106 + k] : (ushort)0;
  }
  if (tid < 100) m4L[tid] = m4[tid];
  __syncthreads();

  // M1: 106->150 relu (jt PK136 -> v1 PK168)
  mfma_layer<4, 10, 150, 0, K2ROWS, false, 2, false>(
      pool, K2_JT_OFF, 136, K2_V1_OFF, 168, wsb + M1B * 64, biasH + BO_MB1,
      nullptr, nullptr, nullptr, nullptr, lane, wid);
  __syncthreads();

  // M2: zero v2 tail; 150->100 relu (v1 -> v2 @0 PK136)
  zero_tail<K2ROWS, 136>(pool, 0, tid);
  mfma_layer<5, 7, 100, 0, K2ROWS, false, 2, false>(
      pool, K2_V1_OFF, 168, 0, 136, wsb + M2B * 64, biasH + BO_MB2,
      nullptr, nullptr, nullptr, nullptr, lane, wid);
  __syncthreads();

  // M3: 100->100 relu (v2 -> v3 @V1_OFF PK136)
  mfma_layer<4, 7, 100, 0, K2ROWS, false, 2, false>(
      pool, 0, 136, K2_V1_OFF, 136, wsb + M3B * 64, biasH + BO_MB3,
      nullptr, nullptr, nullptr, nullptr, lane, wid);
  __syncthreads();

  // M4: 100->1
  {
    const int row = tid >> 2, seg = tid & 3;
    const ushort* v3 = (const ushort*)(pool + K2_V1_OFF);
    float s = 0.f;
    for (int k = seg; k < 100; k += 4) s += h2f(v3[row * 136 + k]) * m4L[k];
    s += __shfl_xor(s, 1);
    s += __shfl_xor(s, 2);
    if (seg == 0) out[r0 + row] = s + mb4[0];
  }
}

extern "C" void kernel_launch(void* const* d_in, const int* in_sizes, int n_in,
                              void* d_out, int out_size, void* d_ws, size_t ws_size,
                              hipStream_t stream) {
  const float* state = (const float*)d_in[0];
  const float* w1 = (const float*)d_in[1];
  const float* b1 = (const float*)d_in[2];
  const float* w2 = (const float*)d_in[3];
  const float* b2 = (const float*)d_in[4];
  const float* w3 = (const float*)d_in[5];
  const float* b3 = (const float*)d_in[6];
  const float* a1 = (const float*)d_in[7];
  const float* ab1 = (const float*)d_in[8];
  const float* a2 = (const float*)d_in[9];
  const float* ab2 = (const float*)d_in[10];
  const float* a3 = (const float*)d_in[11];
  const float* ab3 = (const float*)d_in[12];
  const float* m1 = (const float*)d_in[13];
  const float* mb1 = (const float*)d_in[14];
  const float* m2 = (const float*)d_in[15];
  const float* mb2 = (const float*)d_in[16];
  const float* m3 = (const float*)d_in[17];
  const float* mb3 = (const float*)d_in[18];
  const float* m4 = (const float*)d_in[19];
  const float* mb4 = (const float*)d_in[20];
  float* out = (float*)d_out;
  uint4* ws = (uint4*)d_ws;
  ushort* jointgH = (ushort*)((char*)d_ws + JOINT_BYTE);

  prep_kernel<<<261, 64, 0, stream>>>(w1, w2, w3, a1, a2, m1, m2, m3,
                                      b1, b2, b3, ab1, mb1, mb2, mb3, ws);

  const int B = in_sizes[0] / 260;  // 16384
  value_net_kernel<<<dim3(B / NB), dim3(NTHR), 0, stream>>>(
      state, ab2, a3, ab3, (const uint4*)ws, jointgH);

  mlp2_kernel<<<dim3(B / K2ROWS), dim3(K2THR), 0, stream>>>(
      jointgH, m4, mb4, (const uint4*)ws, out);
}

// Round 19
// 123.788 us; speedup vs baseline: 1.0189x; 1.0189x over previous
//
#include <hip/hip_runtime.h>
#include <math.h>

#define NTHR 512
#define NB 4              // batches per WG (kernel1)
#define NROWSR (NB * 20)  // 80 rows = 5 exact M-tiles

typedef _Float16 h8v __attribute__((ext_vector_type(8)));
typedef _Float16 h2v __attribute__((ext_vector_type(2)));
using f4 = __attribute__((ext_vector_type(4))) float;

__device__ __forceinline__ h2v cvt_pk_h2(float a, float b) {
  return __builtin_bit_cast(h2v, __builtin_amdgcn_cvt_pkrtz(a, b));
}

// kernel1 LDS pool (bytes). Single-plane f16: [rows][PK], 2B/elem.
#define H1_OFF 0
#define H1_PK 168        // 80*168*2 = 26880
#define H2_OFF 26880
#define H2_PK 136        // 80*136*2 = 21760 -> end 48640
#define FEAT_OFF 0       // aliases H1 (dead after L2)
#define FEAT_PK 136
#define S1_OFF 26880     // aliases H2 (dead after L3); [112,128) zeros inherited
#define S1_PK 136
#define XS_OFF 26880     // aliases H2 region during P0/P1 only
#define XS_PK 40         // 80*40*2 = 6400
#define GS_OFF S1_OFF    // GS16: 4 rows x PK136 f16, alive P4->P5 only
#define POOL1 48640

// ws fragment bases (1KB blocks; each (kb,nt) = 2 blocks hi+lo)
#define L1B 0
#define L2B 20
#define L3B 90
#define A1B 146
#define A2B 202
#define M1B 258
#define M2B 338
#define M3B 408
#define A1GB 464          // a1 rows 100..199 (gpart MFMA): 4kb x 7nt x 2
#define BIAS_BYTE 532480  // 520KB: packed f16 biases, 8 regions x 160 ushorts
#define JOINT_BYTE 536576 // f16 joint[16384][106]

// bias region offsets (ushorts)
#define BO_B1 0
#define BO_B2 160
#define BO_B3 320
#define BO_AB1 480
#define BO_MB1 800
#define BO_MB2 960
#define BO_MB3 1120

// kernel2 (f16 single-plane)
#define K2ROWS 64
#define K2THR 256
#define K2_JT_OFF 0      // 64*136*2 = 17408
#define K2_V1_OFF 17408  // 64*168*2 = 21504 -> end 38912
#define K2_POOL 38912

__device__ __forceinline__ float relu_f(float v) { return fmaxf(v, 0.f); }
__device__ __forceinline__ float h2f(ushort u) {
  return (float)__builtin_bit_cast(_Float16, u);
}
__device__ __forceinline__ ushort f2h(float v) {
  return __builtin_bit_cast(ushort, (_Float16)v);
}
__device__ __forceinline__ uint pk2h(float a, float b) {
  return (uint)f2h(a) | ((uint)f2h(b) << 16);
}

// guarded float4 (zeros beyond C)
__device__ __forceinline__ float4 load4_guard(const float* __restrict__ a, int of4, int C) {
  float4 v;
  if (of4 + 3 < C) v = *(const float4*)(a + of4);
  else {
    v.x = (of4 + 0 < C) ? a[of4 + 0] : 0.f;
    v.y = (of4 + 1 < C) ? a[of4 + 1] : 0.f;
    v.z = (of4 + 2 < C) ? a[of4 + 2] : 0.f;
    v.w = (of4 + 3 < C) ? a[of4 + 3] : 0.f;
  }
  return v;
}

// ---------------- prep: pack hi/lo f16 weight fragments + f16 biases ---------
__global__ __launch_bounds__(64) void prep_kernel(
    const float* __restrict__ w1, const float* __restrict__ w2,
    const float* __restrict__ w3, const float* __restrict__ a1,
    const float* __restrict__ a2, const float* __restrict__ m1,
    const float* __restrict__ m2, const float* __restrict__ m3,
    const float* __restrict__ b1, const float* __restrict__ b2,
    const float* __restrict__ b3, const float* __restrict__ ab1,
    const float* __restrict__ mb1, const float* __restrict__ mb2,
    const float* __restrict__ mb3,
    uint4* __restrict__ ws) {
  const int job = blockIdx.x;
  const int lane = threadIdx.x;
  if (job == 260) {  // pack biases -> f16 (zero-padded to 160 each)
    ushort* bh = (ushort*)((char*)ws + BIAS_BYTE);
    for (int idx = lane; idx < 1280; idx += 64) {
      const int reg = idx / 160, off = idx - reg * 160;
      const float* src = nullptr; int C = 0;
      switch (reg) {
        case 0: src = b1;  C = 150; break;
        case 1: src = b2;  C = 100; break;
        case 2: src = b3;  C = 100; break;
        case 3: src = ab1; C = 100; break;
        case 4: src = nullptr; C = 0; break;   // (spare)
        case 5: src = mb1; C = 150; break;
        case 6: src = mb2; C = 100; break;
        default: src = mb3; C = 100; break;
      }
      bh[idx] = (off < C) ? f2h(src[off]) : (ushort)0;
    }
    return;
  }
  const float* W;
  int K, C, NT, base, kb, nt, i;
  if (job < 10)       { W = w1; K = 13;  C = 150; NT = 10; base = L1B; kb = 0; nt = job; }
  else if (job < 45)  { W = w2; K = 150; C = 100; NT = 7;  base = L2B; i = job - 10;  kb = i / 7;  nt = i % 7; }
  else if (job < 73)  { W = w3; K = 100; C = 100; NT = 7;  base = L3B; i = job - 45;  kb = i / 7;  nt = i % 7; }
  else if (job < 101) { W = a1; K = 100; C = 100; NT = 7;  base = A1B; i = job - 73;  kb = i / 7;  nt = i % 7; }
  else if (job < 129) { W = a2; K = 100; C = 100; NT = 7;  base = A2B; i = job - 101; kb = i / 7;  nt = i % 7; }
  else if (job < 169) { W = m1; K = 106; C = 150; NT = 10; base = M1B; i = job - 129; kb = i / 10; nt = i % 10; }
  else if (job < 204) { W = m2; K = 150; C = 100; NT = 7;  base = M2B; i = job - 169; kb = i / 7;  nt = i % 7; }
  else if (job < 232) { W = m3; K = 100; C = 100; NT = 7;  base = M3B; i = job - 204; kb = i / 7;  nt = i % 7; }
  else                { W = a1 + 10000; K = 100; C = 100; NT = 7; base = A1GB; i = job - 232; kb = i / 7; nt = i % 7; }
  const int r = lane & 15, g = lane >> 4;
  const int j = nt * 16 + r;
  uint hi[8], lo[8];
  for (int e = 0; e < 8; ++e) {
    int k = kb * 32 + g * 8 + e;
    float v = (k < K && j < C) ? W[k * C + j] : 0.f;
    _Float16 hh = (_Float16)v;
    float hf = (float)hh;
    _Float16 ll = (_Float16)(v - hf);
    hi[e] = (uint)__builtin_bit_cast(ushort, hh);
    lo[e] = (uint)__builtin_bit_cast(ushort, ll);
  }
  uint4 vh = { hi[0] | (hi[1] << 16), hi[2] | (hi[3] << 16),
               hi[4] | (hi[5] << 16), hi[6] | (hi[7] << 16) };
  uint4 vl = { lo[0] | (lo[1] << 16), lo[2] | (lo[3] << 16),
               lo[4] | (lo[5] << 16), lo[6] | (lo[7] << 16) };
  ws[(size_t)(base + (kb * NT + nt) * 2 + 0) * 64 + lane] = vh;
  ws[(size_t)(base + (kb * NT + nt) * 2 + 1) * 64 + lane] = vl;
}

// ---------------- f16 MFMA dense layer, swapped operands ----------------
// D = W^T x act^T: lane holds 4 consecutive out-features (of..of+3) of ONE
// act row. Packed-f16 epilogue; pad cols compute to exact 0.
// PAIR=true (kernel1): wave owns an nt-PAIR; act fragment read once per mt
// feeds both nt (halves ds_read + addressing). Fits VGPR cap only at TERMS=1.
// TERMS: 1 = single f16 weight term, 2 = hi/lo compensated.
// MODE: 0 relu->f16, 1 linear->f16, 2 relu+gpart->f16,
//       3 relu + a3-dot fold -> sceL atomics (f32 path, biasF)
template <int KB, int NT, int C, int MODE, int ROWS, bool W8, int TERMS, bool PAIR>
__device__ __forceinline__ void mfma_layer(
    char* pool, int inOff, int PKin, int outOff, int PKout,
    const h8v* __restrict__ wsB, const ushort* __restrict__ biasH,
    const float* __restrict__ biasF, const ushort* gpartH, float* sceL,
    const float* __restrict__ a3, int lane, int wid) {
  constexpr int MTL = ROWS / 16;
  const int r = lane & 15, g = lane >> 4;
  const char* Ain = pool + inOff;
  int wlo, mtb, mte;
  if constexpr (W8) {
    wlo = wid & 3;
    const int whi = wid >> 2;
    mtb = whi ? 3 : 0; mte = whi ? MTL : 3;
  } else { wlo = wid; mtb = 0; mte = MTL; }

  if constexpr (PAIR) {
    constexpr int NP2 = (NT + 1) / 2;
    for (int p = wlo; p < NP2; p += 4) {
      const int nt0 = 2 * p;
      const bool two = (nt0 + 1 < NT);
      h8v w0[KB], w1[KB];
#pragma unroll
      for (int kb = 0; kb < KB; ++kb) {
        w0[kb] = wsB[((kb * NT + nt0) * 2 + 0) * 64 + lane];
        if (two) w1[kb] = wsB[((kb * NT + nt0 + 1) * 2 + 0) * 64 + lane];
      }
      const int of0 = nt0 * 16 + g * 4, of1 = of0 + 16;
      uint2 bp0, bp1;
      float4 b40, b41, a340, a341;
      if constexpr (MODE == 3) {
        b40 = load4_guard(biasF, of0, C); a340 = load4_guard(a3, of0, C);
        b41 = load4_guard(biasF, of1, C); a341 = load4_guard(a3, of1, C);
      } else {
        bp0 = *(const uint2*)(biasH + of0);
        bp1 = *(const uint2*)(biasH + of1);   // biasH zero-padded to 160
      }
      for (int mt = mtb; mt < mte; ++mt) {
        const int ar = mt * 16 + r;
        f4 acc0 = {0.f, 0.f, 0.f, 0.f}, acc1 = {0.f, 0.f, 0.f, 0.f};
        const char* aP = Ain + ar * (PKin * 2) + g * 16;
#pragma unroll
        for (int kb = 0; kb < KB; ++kb) {
          h8v a = *(const h8v*)(aP + kb * 64);
          acc0 = __builtin_amdgcn_mfma_f32_16x16x32_f16(w0[kb], a, acc0, 0, 0, 0);
          if (two) acc1 = __builtin_amdgcn_mfma_f32_16x16x32_f16(w1[kb], a, acc1, 0, 0, 0);
        }
        if constexpr (MODE == 3) {
          float v0 = fmaxf(acc0[0] + b40.x, 0.f), v1 = fmaxf(acc0[1] + b40.y, 0.f);
          float v2 = fmaxf(acc0[2] + b40.z, 0.f), v3 = fmaxf(acc0[3] + b40.w, 0.f);
          float val = v0 * a340.x + v1 * a340.y + v2 * a340.z + v3 * a340.w;
          if (two) {
            float u0 = fmaxf(acc1[0] + b41.x, 0.f), u1 = fmaxf(acc1[1] + b41.y, 0.f);
            float u2 = fmaxf(acc1[2] + b41.z, 0.f), u3 = fmaxf(acc1[3] + b41.w, 0.f);
            val += u0 * a341.x + u1 * a341.y + u2 * a341.z + u3 * a341.w;
          }
          val += __shfl_xor(val, 16);
          val += __shfl_xor(val, 32);
          if (lane < 16) atomicAdd(&sceL[ar], val);
        } else {
          h2v lo = cvt_pk_h2(acc0[0], acc0[1]);
          h2v hi = cvt_pk_h2(acc0[2], acc0[3]);
          lo += __builtin_bit_cast(h2v, bp0.x);
          hi += __builtin_bit_cast(h2v, bp0.y);
          if constexpr (MODE == 2) {
            uint2 gp = *(const uint2*)(gpartH + (ar / 20) * 112 + of0);
            lo += __builtin_bit_cast(h2v, gp.x);
            hi += __builtin_bit_cast(h2v, gp.y);
          }
          if constexpr (MODE != 1) {
            h2v z = {(_Float16)0.f, (_Float16)0.f};
            lo = __builtin_elementwise_max(lo, z);
            hi = __builtin_elementwise_max(hi, z);
          }
          *(uint2*)((ushort*)(pool + outOff) + ar * PKout + of0) =
              uint2{__builtin_bit_cast(uint, lo), __builtin_bit_cast(uint, hi)};
          if (two) {
            h2v lo1 = cvt_pk_h2(acc1[0], acc1[1]);
            h2v hi1 = cvt_pk_h2(acc1[2], acc1[3]);
            lo1 += __builtin_bit_cast(h2v, bp1.x);
            hi1 += __builtin_bit_cast(h2v, bp1.y);
            if constexpr (MODE == 2) {
              uint2 gp1 = *(const uint2*)(gpartH + (ar / 20) * 112 + of1);
              lo1 += __builtin_bit_cast(h2v, gp1.x);
              hi1 += __builtin_bit_cast(h2v, gp1.y);
            }
            if constexpr (MODE != 1) {
              h2v z = {(_Float16)0.f, (_Float16)0.f};
              lo1 = __builtin_elementwise_max(lo1, z);
              hi1 = __builtin_elementwise_max(hi1, z);
            }
            *(uint2*)((ushort*)(pool + outOff) + ar * PKout + of1) =
                uint2{__builtin_bit_cast(uint, lo1), __builtin_bit_cast(uint, hi1)};
          }
        }
      }
    }
  } else {
    for (int nt = wlo; nt < NT; nt += 4) {
      h8v wh[KB], wl[KB];
#pragma unroll
      for (int kb = 0; kb < KB; ++kb) {
        wh[kb] = wsB[((kb * NT + nt) * 2 + 0) * 64 + lane];
        if constexpr (TERMS == 2)
          wl[kb] = wsB[((kb * NT + nt) * 2 + 1) * 64 + lane];
      }
      const int of = nt * 16 + g * 4;
      uint2 bp;
      float4 b4, a34;
      if constexpr (MODE == 3) {
        b4 = load4_guard(biasF, of, C);
        a34 = load4_guard(a3, of, C);
      } else {
        bp = *(const uint2*)(biasH + of);
      }
      for (int mt = mtb; mt < mte; ++mt) {
        const int ar = mt * 16 + r;
        f4 acc = {0.f, 0.f, 0.f, 0.f};
        const char* aP = Ain + ar * (PKin * 2) + g * 16;
#pragma unroll
        for (int kb = 0; kb < KB; ++kb) {
          h8v a = *(const h8v*)(aP + kb * 64);
          acc = __builtin_amdgcn_mfma_f32_16x16x32_f16(wh[kb], a, acc, 0, 0, 0);
          if constexpr (TERMS == 2)
            acc = __builtin_amdgcn_mfma_f32_16x16x32_f16(wl[kb], a, acc, 0, 0, 0);
        }
        if constexpr (MODE == 3) {
          float v0 = fmaxf(acc[0] + b4.x, 0.f), v1 = fmaxf(acc[1] + b4.y, 0.f);
          float v2 = fmaxf(acc[2] + b4.z, 0.f), v3 = fmaxf(acc[3] + b4.w, 0.f);
          float val = v0 * a34.x + v1 * a34.y + v2 * a34.z + v3 * a34.w;
          val += __shfl_xor(val, 16);
          val += __shfl_xor(val, 32);
          if (lane < 16) atomicAdd(&sceL[ar], val);
        } else {
          h2v lo = cvt_pk_h2(acc[0], acc[1]);
          h2v hi = cvt_pk_h2(acc[2], acc[3]);
          lo += __builtin_bit_cast(h2v, bp.x);
          hi += __builtin_bit_cast(h2v, bp.y);
          if constexpr (MODE == 2) {
            uint2 gp = *(const uint2*)(gpartH + (ar / 20) * 112 + of);
            lo += __builtin_bit_cast(h2v, gp.x);
            hi += __builtin_bit_cast(h2v, gp.y);
          }
          if constexpr (MODE != 1) {
            h2v z = {(_Float16)0.f, (_Float16)0.f};
            lo = __builtin_elementwise_max(lo, z);
            hi = __builtin_elementwise_max(hi, z);
          }
          *(uint2*)((ushort*)(pool + outOff) + ar * PKout + of) =
              uint2{__builtin_bit_cast(uint, lo), __builtin_bit_cast(uint, hi)};
        }
      }
    }
  }
}

// zero cols [112,128) of an f16 [ROWSZ][PK] buffer
template <int ROWSZ, int PK>
__device__ __forceinline__ void zero_tail(char* pool, int off, int tid) {
  if (tid < ROWSZ) {
    uint4* z = (uint4*)((ushort*)(pool + off) + (size_t)tid * PK + 112);
    z[0] = uint4{0, 0, 0, 0};
    z[1] = uint4{0, 0, 0, 0};
  }
}

// ---------------- kernel1: 4 batches per 512-thr WG ----------------
__global__ __launch_bounds__(NTHR, 6) void value_net_kernel(
    const float* __restrict__ state,
    const float* __restrict__ ab2,
    const float* __restrict__ a3, const float* __restrict__ ab3,
    const uint4* __restrict__ ws, ushort* __restrict__ jointgH) {
  __shared__ char pool[POOL1];
  __shared__ ushort gpartH[NB * 112];
  __shared__ float sceL[NROWSR], swL[NROWSR];

  const int tid = threadIdx.x;
  const int lane = tid & 63, wid = tid >> 6;
  const int b0 = blockIdx.x * NB;
  const h8v* wsb = (const h8v*)ws;
  const ushort* biasH = (const ushort*)((const char*)ws + BIAS_BYTE);

  // P0: stage state -> XS f16 (80 x PK40, cols 13..39 zero); zero sceL
  for (int i = tid; i < NROWSR * XS_PK; i += NTHR) {
    int row = i / XS_PK, k = i - row * XS_PK;
    float v = (k < 13) ? state[((size_t)b0 * 20 + row) * 13 + k] : 0.f;
    ((ushort*)(pool + XS_OFF))[row * XS_PK + k] = f2h(v);
  }
  if (tid < NROWSR) sceL[tid] = 0.f;
  __syncthreads();

  // P1: L1 13->150 relu  XS -> H1
  mfma_layer<1, 10, 150, 0, NROWSR, true, 1, true>(
      pool, XS_OFF, XS_PK, H1_OFF, H1_PK, wsb + L1B * 64, biasH + BO_B1,
      nullptr, nullptr, nullptr, nullptr, lane, wid);
  __syncthreads();

  // P2: zero H2 tail; L2 150->100 relu  H1 -> H2
  zero_tail<NROWSR, H2_PK>(pool, H2_OFF, tid);
  mfma_layer<5, 7, 100, 0, NROWSR, true, 1, true>(
      pool, H1_OFF, H1_PK, H2_OFF, H2_PK, wsb + L2B * 64, biasH + BO_B2,
      nullptr, nullptr, nullptr, nullptr, lane, wid);
  __syncthreads();

  // P3: zero FEAT tail; L3 100->100 linear  H2 -> FEAT
  zero_tail<NROWSR, FEAT_PK>(pool, FEAT_OFF, tid);
  mfma_layer<4, 7, 100, 1, NROWSR, true, 1, true>(
      pool, H2_OFF, H2_PK, FEAT_OFF, FEAT_PK, wsb + L3B * 64, biasH + BO_B3,
      nullptr, nullptr, nullptr, nullptr, lane, wid);
  __syncthreads();

  // P4: gs = mean over n (x0.05) -> GS16 f16 tile (cols [100,128) zero)
  if (tid < NB * 100) {
    const int b = tid / 100, d = tid - b * 100;
    const ushort* f = (const ushort*)(pool + FEAT_OFF);
    float s = 0.f;
    for (int n = 0; n < 20; ++n) s += h2f(f[(b * 20 + n) * FEAT_PK + d]);
    ((ushort*)(pool + GS_OFF))[b * 136 + d] = f2h(s * 0.05f);
  } else if (tid < NB * 100 + NB * 28) {
    const int idx = tid - NB * 100;
    ((ushort*)(pool + GS_OFF))[(idx / 28) * 136 + 100 + (idx % 28)] = 0;
  }
  __syncthreads();

  // P5: gpart = gs @ a1[100:200] via MFMA -> gpartH f16 (stride 112, pad 0)
  if (wid < 7) {
    const int r = lane & 15, g = lane >> 4;
    const int nt = wid;
    const h8v* wsg = wsb + A1GB * 64;
    h8v wh[4];
#pragma unroll
    for (int kb = 0; kb < 4; ++kb)
      wh[kb] = wsg[((kb * 7 + nt) * 2 + 0) * 64 + lane];
    const char* aP = pool + GS_OFF + (r & 3) * (136 * 2) + g * 16;
    f4 acc = {0.f, 0.f, 0.f, 0.f};
#pragma unroll
    for (int kb = 0; kb < 4; ++kb) {
      h8v a = *(const h8v*)(aP + kb * 64);
      acc = __builtin_amdgcn_mfma_f32_16x16x32_f16(wh[kb], a, acc, 0, 0, 0);
    }
    const int of = nt * 16 + g * 4;
    if (r < 4) {
      uint2 pk = { pk2h(acc[0], acc[1]), pk2h(acc[2], acc[3]) };
      *(uint2*)(gpartH + r * 112 + of) = pk;
    }
  }
  __syncthreads();

  // P6: A1 (feat half) + gpart, relu  FEAT -> S1
  mfma_layer<4, 7, 100, 2, NROWSR, true, 1, true>(
      pool, FEAT_OFF, FEAT_PK, S1_OFF, S1_PK, wsb + A1B * 64, biasH + BO_AB1,
      nullptr, gpartH, nullptr, nullptr, lane, wid);
  __syncthreads();

  // P7: A2 relu + A3-dot fold -> sceL atomics (f32 path)
  mfma_layer<4, 7, 100, 3, NROWSR, true, 1, true>(
      pool, S1_OFF, S1_PK, 0, 0, wsb + A2B * 64, nullptr,
      ab2, nullptr, sceL, a3, lane, wid);
  __syncthreads();

  // P8: softmax over n, wave-parallel (32-lane group per batch)
  if (tid < 128) {
    const int b = tid >> 5, l = tid & 31;
    const float ab3v = ab3[0];
    float s = (l < 20) ? relu_f(sceL[b * 20 + l] + ab3v) : -1e30f;
    float m = s;
#pragma unroll
    for (int d = 1; d < 32; d <<= 1) m = fmaxf(m, __shfl_xor(m, d));
    float e = (l < 20) ? __expf(s - m) : 0.f;
    float sum = e;
#pragma unroll
    for (int d = 1; d < 32; d <<= 1) sum += __shfl_xor(sum, d);
    if (l < 20) swL[b * 20 + l] = e / sum;
  }
  __syncthreads();

  // P9: weighted feature -> jointgH f16 (800 items); self (24 items)
  for (int it = tid; it < NB * 200; it += NTHR) {
    const int b = it / 200, rem = it - b * 200;
    const int d = rem >> 1, half = rem & 1;
    const ushort* f = (const ushort*)(pool + FEAT_OFF);
    float acc = 0.f;
    for (int n = half * 10; n < half * 10 + 10; ++n)
      acc += swL[b * 20 + n] * h2f(f[(b * 20 + n) * FEAT_PK + d]);
    acc += __shfl_xor(acc, 1);
    if (half == 0) jointgH[(size_t)(b0 + b) * 106 + 6 + d] = f2h(acc);
  }
  if (tid < NB * 6) {
    const int b = tid / 6, i = tid - b * 6;
    jointgH[(size_t)(b0 + b) * 106 + i] = f2h(state[((size_t)(b0 + b)) * 260 + i]);
  }
}

// ---------------- kernel2: M-MLP GEMM over 16384 rows (f16, 2-term) ----------
__global__ __launch_bounds__(K2THR) void mlp2_kernel(
    const ushort* __restrict__ jointgH,
    const float* __restrict__ m4, const float* __restrict__ mb4,
    const uint4* __restrict__ ws, float* __restrict__ out) {
  __shared__ char pool[K2_POOL];
  __shared__ float m4L[100];
  const int tid = threadIdx.x, lane = tid & 63, wid = tid >> 6;
  const size_t r0 = (size_t)blockIdx.x * K2ROWS;
  const h8v* wsb = (const h8v*)ws;
  const ushort* biasH = (const ushort*)((const char*)ws + BIAS_BYTE);

  // stage joint f16 -> LDS (PK=136, cols 106..135 zero); m4 -> LDS
  for (int i = tid; i < K2ROWS * 136; i += K2THR) {
    int row = i / 136, k = i - row * 136;
    ((ushort*)(pool + K2_JT_OFF))[row * 136 + k] =
        (k < 106) ? jointgH[(r0 + row) * 106 + k] : (ushort)0;
  }
  if (tid < 100) m4L[tid] = m4[tid];
  __syncthreads();

  // M1: 106->150 relu (jt PK136 -> v1 PK168)
  mfma_layer<4, 10, 150, 0, K2ROWS, false, 2, false>(
      pool, K2_JT_OFF, 136, K2_V1_OFF, 168, wsb + M1B * 64, biasH + BO_MB1,
      nullptr, nullptr, nullptr, nullptr, lane, wid);
  __syncthreads();

  // M2: zero v2 tail; 150->100 relu (v1 -> v2 @0 PK136)
  zero_tail<K2ROWS, 136>(pool, 0, tid);
  mfma_layer<5, 7, 100, 0, K2ROWS, false, 2, false>(
      pool, K2_V1_OFF, 168, 0, 136, wsb + M2B * 64, biasH + BO_MB2,
      nullptr, nullptr, nullptr, nullptr, lane, wid);
  __syncthreads();

  // M3: 100->100 relu (v2 -> v3 @V1_OFF PK136)
  mfma_layer<4, 7, 100, 0, K2ROWS, false, 2, false>(
      pool, 0, 136, K2_V1_OFF, 136, wsb + M3B * 64, biasH + BO_MB3,
      nullptr, nullptr, nullptr, nullptr, lane, wid);
  __syncthreads();

  // M4: 100->1
  {
    const int row = tid >> 2, seg = tid & 3;
    const ushort* v3 = (const ushort*)(pool + K2_V1_OFF);
    float s = 0.f;
    for (int k = seg; k < 100; k += 4) s += h2f(v3[row * 136 + k]) * m4L[k];
    s += __shfl_xor(s, 1);
    s += __shfl_xor(s, 2);
    if (seg == 0) out[r0 + row] = s + mb4[0];
  }
}

extern "C" void kernel_launch(void* const* d_in, const int* in_sizes, int n_in,
                              void* d_out, int out_size, void* d_ws, size_t ws_size,
                              hipStream_t stream) {
  const float* state = (const float*)d_in[0];
  const float* w1 = (const float*)d_in[1];
  const float* b1 = (const float*)d_in[2];
  const float* w2 = (const float*)d_in[3];
  const float* b2 = (const float*)d_in[4];
  const float* w3 = (const float*)d_in[5];
  const float* b3 = (const float*)d_in[6];
  const float* a1 = (const float*)d_in[7];
  const float* ab1 = (const float*)d_in[8];
  const float* a2 = (const float*)d_in[9];
  const float* ab2 = (const float*)d_in[10];
  const float* a3 = (const float*)d_in[11];
  const float* ab3 = (const float*)d_in[12];
  const float* m1 = (const float*)d_in[13];
  const float* mb1 = (const float*)d_in[14];
  const float* m2 = (const float*)d_in[15];
  const float* mb2 = (const float*)d_in[16];
  const float* m3 = (const float*)d_in[17];
  const float* mb3 = (const float*)d_in[18];
  const float* m4 = (const float*)d_in[19];
  const float* mb4 = (const float*)d_in[20];
  float* out = (float*)d_out;
  uint4* ws = (uint4*)d_ws;
  ushort* jointgH = (ushort*)((char*)d_ws + JOINT_BYTE);

  prep_kernel<<<261, 64, 0, stream>>>(w1, w2, w3, a1, a2, m1, m2, m3,
                                      b1, b2, b3, ab1, mb1, mb2, mb3, ws);

  const int B = in_sizes[0] / 260;  // 16384
  value_net_kernel<<<dim3(B / NB), dim3(NTHR), 0, stream>>>(
      state, ab2, a3, ab3, (const uint4*)ws, jointgH);

  mlp2_kernel<<<dim3(B / K2ROWS), dim3(K2THR), 0, stream>>>(
      jointgH, m4, mb4, (const uint4*)ws, out);
}